// Round 7
// baseline (340.592 us; speedup 1.0000x reference)
//
#include <hip/hip_runtime.h>
#include <hip/hip_bf16.h>
#include <cstddef>

typedef _Float16 f16;
typedef _Float16 f16x8 __attribute__((ext_vector_type(8)));
typedef _Float16 f16x4 __attribute__((ext_vector_type(4)));
typedef _Float16 f16x2 __attribute__((ext_vector_type(2)));
typedef float    f32x4 __attribute__((ext_vector_type(4)));

#define MFMA16(a,b,c) __builtin_amdgcn_mfma_f32_16x16x32_f16((a),(b),(c),0,0,0)

__device__ __forceinline__ void gload16(const void* g, void* lds) {
  __builtin_amdgcn_global_load_lds((const __attribute__((address_space(1))) void*)g,
                                   (__attribute__((address_space(3))) void*)lds, 16, 0, 0);
}

// ---------------------------------------------------------------------------
// Prep kernel: blocks [0,1280) convert the 5 weight matrices fp32->f16;
// blocks [1280,2304) build the sinusoidal PE table (f16).
// ---------------------------------------------------------------------------
__global__ __launch_bounds__(256) void prep_kernel(
    const float* __restrict__ w0, const float* __restrict__ w1,
    const float* __restrict__ w2, const float* __restrict__ w3,
    const float* __restrict__ w4, f16* __restrict__ dst,
    f16* __restrict__ pe)
{
  if (blockIdx.x < 1280) {
    const int idx = blockIdx.x * 256 + threadIdx.x;   // float4 units
    const int seg = idx >> 16;
    const int r   = idx & 65535;
    const float* s = seg == 0 ? w0 : seg == 1 ? w1 : seg == 2 ? w2 : seg == 3 ? w3 : w4;
    float4 v = ((const float4*)s)[r];
    f16x4 h = { (f16)v.x, (f16)v.y, (f16)v.z, (f16)v.w };
    ((f16x4*)(dst + ((size_t)seg << 18)))[r] = h;
  } else {
    const int l = blockIdx.x - 1280;
    const int p = threadIdx.x;
    const float divv = expf(-(logf(10000.0f) * (2.0f * (float)p)) / 512.0f);
    const float ang  = (float)l * divv;
    f16x2 o = { (f16)sinf(ang), (f16)cosf(ang) };
    *(f16x2*)(pe + (size_t)l * 512 + 2 * p) = o;
  }
}

// ---------------------------------------------------------------------------
// Main projection GEMM, 128x128 tile (m97 structure), BK=64, 4 waves 2x2,
// 4x4 fragments/wave. blockIdx.z: 0=Q, 1=K, 2=V(transposed out), 3=pos
// (A = pe16 f16, M=1024 -> only x<8 active, no bias, out (H,L,D)).
// ---------------------------------------------------------------------------
__global__ __launch_bounds__(256) void gemm_main(
    const float* __restrict__ q_in, const float* __restrict__ k_in,
    const float* __restrict__ v_in, const f16* __restrict__ pe16,
    const f16* __restrict__ W16,
    const float* __restrict__ bq, const float* __restrict__ bk,
    const float* __restrict__ bv,
    f16* __restrict__ Qf, f16* __restrict__ Kf, f16* __restrict__ Vtf,
    f16* __restrict__ Pf)
{
  const int z = blockIdx.z;
  if (z == 3 && blockIdx.x >= 8) return;

  __shared__ __align__(16) char Asm[16384];   // 128 rows x 128 B (swizzled)
  __shared__ __align__(16) char Bsm[16384];

  const float* Ap   = z == 0 ? q_in : z == 1 ? k_in : v_in;
  const f16*   Wf   = W16 + (size_t)z * 262144;
  const float* bias = z == 0 ? bq : z == 1 ? bk : z == 2 ? bv : nullptr;
  f16*         Cp   = z == 0 ? Qf : z == 1 ? Kf : z == 2 ? Vtf : Pf;

  const int tid   = threadIdx.x;
  const int gm0   = blockIdx.x * 128;
  const int gn0   = blockIdx.y * 128;
  const int lane  = tid & 63, w = tid >> 6;
  const int row16 = lane & 15, grp = lane >> 4;
  const int wm = w & 1, wn = w >> 1;
  const int lr8  = lane >> 3;
  const int swcb = ((lane & 7) ^ lr8) * 16;

  f32x4 acc[4][4];
#pragma unroll
  for (int i = 0; i < 4; ++i)
#pragma unroll
    for (int j = 0; j < 4; ++j)
#pragma unroll
      for (int r = 0; r < 4; ++r) acc[i][j][r] = 0.f;

  for (int k0 = 0; k0 < 512; k0 += 64) {
    __syncthreads();
    float4 areg[8];
    if (z != 3) {
#pragma unroll
      for (int i = 0; i < 8; ++i) {
        const int u = tid + i * 256;
        const int row = u >> 4, cf = (u & 15) * 4;
        areg[i] = *(const float4*)(Ap + (size_t)(gm0 + row) * 512 + k0 + cf);
      }
    } else {
#pragma unroll
      for (int i = 0; i < 4; ++i) {
        const int rA = w * 32 + i * 8;
        gload16((const char*)pe16 + ((size_t)(gm0 + rA + lr8)) * 1024 + (size_t)k0 * 2 + swcb,
                Asm + rA * 128);
      }
    }
#pragma unroll
    for (int i = 0; i < 4; ++i) {
      const int rB = w * 32 + i * 8;
      gload16((const char*)Wf + ((size_t)(gn0 + rB + lr8)) * 1024 + (size_t)k0 * 2 + swcb,
              Bsm + rB * 128);
    }
    if (z != 3) {
#pragma unroll
      for (int i = 0; i < 8; ++i) {
        const int u = tid + i * 256;
        const int row = u >> 4, cf = (u & 15) * 4;
        f16x4 hv = { (f16)areg[i].x, (f16)areg[i].y, (f16)areg[i].z, (f16)areg[i].w };
        *(f16x4*)(Asm + row * 128 + ((cf * 2) ^ ((row & 7) * 16))) = hv;
      }
    }
    asm volatile("s_waitcnt vmcnt(0)" ::: "memory");
    __syncthreads();
#pragma unroll
    for (int kk = 0; kk < 64; kk += 32) {
      const int cb = (kk + 8 * grp) * 2;
      f16x8 af[4], bf[4];
#pragma unroll
      for (int f = 0; f < 4; ++f) {
        const int ra = wm * 64 + f * 16 + row16;
        const int rb = wn * 64 + f * 16 + row16;
        af[f] = *(const f16x8*)(Asm + ra * 128 + (cb ^ ((ra & 7) * 16)));
        bf[f] = *(const f16x8*)(Bsm + rb * 128 + (cb ^ ((rb & 7) * 16)));
      }
#pragma unroll
      for (int fi = 0; fi < 4; ++fi)
#pragma unroll
        for (int fj = 0; fj < 4; ++fj)
          acc[fi][fj] = MFMA16(af[fi], bf[fj], acc[fi][fj]);
    }
  }

#pragma unroll
  for (int fi = 0; fi < 4; ++fi)
#pragma unroll
    for (int fj = 0; fj < 4; ++fj) {
      const int gc = gn0 + wn * 64 + fj * 16 + row16;
      const float bval = (z == 3) ? 0.f : bias[gc];
#pragma unroll
      for (int r = 0; r < 4; ++r) {
        const int gr = gm0 + wm * 64 + fi * 16 + grp * 4 + r;
        const float v = acc[fi][fj][r] + bval;
        const int h = gc >> 5, d = gc & 31;
        if (z == 3) {
          Cp[(((size_t)h) * 1024 + gr) * 32 + d] = (f16)v;
        } else {
          const int b = gr >> 10, l = gr & 1023;
          if (z != 2) {
            Cp[(((size_t)(b * 16 + h)) * 1024 + l) * 32 + d] = (f16)v;
          } else {
            Cp[(((size_t)(b * 16 + h)) * 32 + d) * 1024 + l] = (f16)v;
          }
        }
      }
    }
}

// ---------------------------------------------------------------------------
// Output projection: A = ctx f16, out fp32 row-major + bias. Same 128x128.
// ---------------------------------------------------------------------------
__global__ __launch_bounds__(256) void gemm_out(
    const f16* __restrict__ Ap, const f16* __restrict__ Wf,
    const float* __restrict__ bias, float* __restrict__ Cp)
{
  __shared__ __align__(16) char Asm[16384];
  __shared__ __align__(16) char Bsm[16384];

  const int tid   = threadIdx.x;
  const int gm0   = blockIdx.x * 128;
  const int gn0   = blockIdx.y * 128;
  const int lane  = tid & 63, w = tid >> 6;
  const int row16 = lane & 15, grp = lane >> 4;
  const int wm = w & 1, wn = w >> 1;
  const int lr8  = lane >> 3;
  const int swcb = ((lane & 7) ^ lr8) * 16;

  f32x4 acc[4][4];
#pragma unroll
  for (int i = 0; i < 4; ++i)
#pragma unroll
    for (int j = 0; j < 4; ++j)
#pragma unroll
      for (int r = 0; r < 4; ++r) acc[i][j][r] = 0.f;

  for (int k0 = 0; k0 < 512; k0 += 64) {
    __syncthreads();
#pragma unroll
    for (int i = 0; i < 4; ++i) {
      const int rr = w * 32 + i * 8;
      gload16((const char*)Ap + ((size_t)(gm0 + rr + lr8)) * 1024 + (size_t)k0 * 2 + swcb,
              Asm + rr * 128);
      gload16((const char*)Wf + ((size_t)(gn0 + rr + lr8)) * 1024 + (size_t)k0 * 2 + swcb,
              Bsm + rr * 128);
    }
    asm volatile("s_waitcnt vmcnt(0)" ::: "memory");
    __syncthreads();
#pragma unroll
    for (int kk = 0; kk < 64; kk += 32) {
      const int cb = (kk + 8 * grp) * 2;
      f16x8 af[4], bf[4];
#pragma unroll
      for (int f = 0; f < 4; ++f) {
        const int ra = wm * 64 + f * 16 + row16;
        const int rb = wn * 64 + f * 16 + row16;
        af[f] = *(const f16x8*)(Asm + ra * 128 + (cb ^ ((ra & 7) * 16)));
        bf[f] = *(const f16x8*)(Bsm + rb * 128 + (cb ^ ((rb & 7) * 16)));
      }
#pragma unroll
      for (int fi = 0; fi < 4; ++fi)
#pragma unroll
        for (int fj = 0; fj < 4; ++fj)
          acc[fi][fj] = MFMA16(af[fi], bf[fj], acc[fi][fj]);
    }
  }

#pragma unroll
  for (int fi = 0; fi < 4; ++fi)
#pragma unroll
    for (int fj = 0; fj < 4; ++fj) {
      const int gc = gn0 + wn * 64 + fj * 16 + row16;
      const float bval = bias[gc];
#pragma unroll
      for (int r = 0; r < 4; ++r) {
        const int gr = gm0 + wm * 64 + fi * 16 + grp * 4 + r;
        Cp[(size_t)gr * 512 + gc] = acc[fi][fj][r] + bval;
      }
    }
}

// ---------------------------------------------------------------------------
// Fused rel-pos flash attention (round-3 algorithm, ptile removed).
// P_lds holds UNSHIFTED P * scale f16, stride 1028 (+3 rel-shift-on-read
// trick, col 1024 zeroed). PV A-fragment is built from the exp output by
// in-wave shuffles instead of an LDS bounce:
//   A-frag word w (pair e=2w,2w+1) of chunk kc at lane (q=row16, G=grp)
//     = packed pair X[2kc+(G>>1)][w&1] taken from lane row16+32(G&1)+16(w>>1)
//   where X[c][j] = pack(p[16c+4g+2j], p[16c+4g+2j+1]) in ST layout.
// LDS: 34952 B -> 4 blocks/CU (was 3).
// ---------------------------------------------------------------------------
__global__ __launch_bounds__(256) void attn_kernel(
    const f16* __restrict__ Qf, const f16* __restrict__ Kf,
    const f16* __restrict__ Vt, const f16* __restrict__ Pos,
    const float* __restrict__ ubias, const float* __restrict__ vbias,
    f16* __restrict__ ctx)
{
  __shared__ f16 P_lds[17][1028];     // unshifted P * scale, f16

  const int tid   = threadIdx.x;
  const int w     = tid >> 6, lane = tid & 63;
  const int row16 = lane & 15, grp = lane >> 4;
  const int b = blockIdx.z, h = blockIdx.y;
  const int l0 = blockIdx.x * 16;

  const size_t bh = (size_t)(b * 16 + h);
  const f16* Qb = Qf + bh * 1024 * 32;
  const f16* Kb = Kf + bh * 1024 * 32;
  const f16* Vb = Vt + bh * 32 * 1024;
  const f16* Pb = Pos + (size_t)h * 1024 * 32;

  const f32x4 z4 = {0.f, 0.f, 0.f, 0.f};
  const float scale = 0.04419417382f;   // 1/sqrt(512)

  // --- Phase 0: Q fragments (q = row16, d = 8*grp+e)
  f16x8 qu, qv, qv2;
  {
    f16x8 qraw = *(const f16x8*)(Qb + (size_t)(l0 + row16) * 32 + 8 * grp);
    const int r2 = l0 + 16 + row16;
    f16x8 q2 = *(const f16x8*)(Qb + (size_t)(r2 < 1024 ? r2 : 1023) * 32 + 8 * grp);
#pragma unroll
    for (int e = 0; e < 8; ++e) {
      const float u = ubias[h * 32 + 8 * grp + e];
      const float v = vbias[h * 32 + 8 * grp + e];
      qu[e]  = (f16)((float)qraw[e] + u);
      qv[e]  = (f16)((float)qraw[e] + v);
      qv2[e] = (f16)((float)q2[e]   + v);
    }
  }

  // zero-pad column (j == 1024)
  if (tid < 17) {
    f16x4 z = {(f16)0.f, (f16)0.f, (f16)0.f, (f16)0.f};
    *(f16x4*)&P_lds[tid][1024] = z;
  }

  // --- Phase 1: unshifted P (pre-scaled)
#pragma unroll 4
  for (int c = 0; c < 16; ++c) {
    const int jc = w * 16 + c;
    f16x8 pf = *(const f16x8*)(Pb + (size_t)(jc * 16 + row16) * 32 + 8 * grp);
    f32x4 p0 = MFMA16(pf, qv,  z4);
    f32x4 p1 = MFMA16(pf, qv2, z4);
    const int j0 = jc * 16 + grp * 4;
    {
      f16x4 vv = { (f16)(p0[0] * scale), (f16)(p0[1] * scale),
                   (f16)(p0[2] * scale), (f16)(p0[3] * scale) };
      *(f16x4*)&P_lds[row16][j0] = vv;
    }
    if (row16 == 0) {
      f16x4 vv = { (f16)(p1[0] * scale), (f16)(p1[1] * scale),
                   (f16)(p1[2] * scale), (f16)(p1[3] * scale) };
      *(f16x4*)&P_lds[16][j0] = vv;
    }
  }
  __syncthreads();

  // --- Phase 2: flash loop, wave-private, no barriers, no max tracking
  float psum = 0.f;
  f32x4 od[2];
#pragma unroll
  for (int hh = 0; hh < 2; ++hh) for (int r = 0; r < 4; ++r) od[hh][r] = 0.f;

  const int  c1   = 1023 - l0 - row16;
  const f16* Prow = &P_lds[row16][0];
  const int  sbase = row16 + ((grp & 1) << 5);   // shuffle src base lane
  const bool hiG   = (grp & 2) != 0;

  for (int ti = 0; ti < 4; ++ti) {
    const int mbase = w * 256 + ti * 64;
    f32x4 st[4];
#pragma unroll
    for (int c = 0; c < 4; ++c) {
      f16x8 kf = *(const f16x8*)(Kb + (size_t)(mbase + c * 16 + row16) * 32 + 8 * grp);
      st[c] = MFMA16(kf, qu, z4);
    }

    // exp -> packed ST-layout pairs X[c][j]
    unsigned X[4][2];
#pragma unroll
    for (int c = 0; c < 4; ++c) {
      float p[4];
#pragma unroll
      for (int r = 0; r < 4; ++r) {
        const int jA  = mbase + c * 16 + grp * 4 + r + c1;
        const int idx = jA + (jA >= 1025 ? 3 : 0);
        const float sh = (float)Prow[idx];
        const float s  = fmaf(st[c][r], scale, sh);
        p[r] = __expf(s);
        psum += p[r];
      }
      f16x2 t0 = { (f16)p[0], (f16)p[1] };
      f16x2 t1 = { (f16)p[2], (f16)p[3] };
      X[c][0] = __builtin_bit_cast(unsigned, t0);
      X[c][1] = __builtin_bit_cast(unsigned, t1);
    }

    // shuffle-redistribute into K=32 A-fragments, then PV MFMA
#pragma unroll
    for (int kc = 0; kc < 2; ++kc) {
      union { unsigned u[4]; f16x8 v; } pa;
#pragma unroll
      for (int wd = 0; wd < 4; ++wd) {
        const int src = sbase + ((wd >> 1) << 4);
        const unsigned lo = (unsigned)__shfl((int)X[2 * kc][wd & 1], src, 64);
        const unsigned hi = (unsigned)__shfl((int)X[2 * kc + 1][wd & 1], src, 64);
        pa.u[wd] = hiG ? hi : lo;
      }
#pragma unroll
      for (int hh = 0; hh < 2; ++hh) {
        f16x8 vf = *(const f16x8*)(Vb + (size_t)(hh * 16 + row16) * 1024 + mbase + kc * 32 + 8 * grp);
        od[hh] = MFMA16(pa.v, vf, od[hh]);
      }
    }
  }

  float l1 = psum + __shfl_xor(psum, 16);
  l1 += __shfl_xor(l1, 32);

  __syncthreads();
  float* mo = (float*)&P_lds[0][0];    // overlay: [4][16 q][32 d]
  float* ls = mo + 4 * 16 * 32;        // [4][16]
#pragma unroll
  for (int hh = 0; hh < 2; ++hh)
#pragma unroll
    for (int r = 0; r < 4; ++r)
      mo[(w * 16 + grp * 4 + r) * 32 + hh * 16 + row16] = od[hh][r];
  if (grp == 0) ls[w * 16 + row16] = l1;
  __syncthreads();

  const int q = tid >> 4, dp = tid & 15;
  const float Ls = ls[q] + ls[16 + q] + ls[32 + q] + ls[48 + q];
  float o0 = 0.f, o1 = 0.f;
#pragma unroll
  for (int ww = 0; ww < 4; ++ww) {
    o0 += mo[(ww * 16 + q) * 32 + 2 * dp];
    o1 += mo[(ww * 16 + q) * 32 + 2 * dp + 1];
  }
  const float inv = 1.f / Ls;
  const size_t oidx = ((size_t)(b * 1024 + l0 + q)) * 512 + h * 32 + 2 * dp;
  f16x2 o2 = { (f16)(o0 * inv), (f16)(o1 * inv) };
  *(f16x2*)(ctx + oidx) = o2;
}

// ---------------------------------------------------------------------------
extern "C" void kernel_launch(void* const* d_in, const int* in_sizes, int n_in,
                              void* d_out, int out_size, void* d_ws, size_t ws_size,
                              hipStream_t stream) {
  const float* query  = (const float*)d_in[0];
  const float* key_in = (const float*)d_in[1];
  const float* value  = (const float*)d_in[2];
  const float* Wq = (const float*)d_in[3];
  const float* bq = (const float*)d_in[4];
  const float* Wk = (const float*)d_in[5];
  const float* bk = (const float*)d_in[6];
  const float* Wv = (const float*)d_in[7];
  const float* bv = (const float*)d_in[8];
  const float* Wpos = (const float*)d_in[9];
  const float* ub   = (const float*)d_in[10];
  const float* vb   = (const float*)d_in[11];
  const float* Wo = (const float*)d_in[12];
  const float* bo = (const float*)d_in[13];
  float* out = (float*)d_out;

  char* ws = (char*)d_ws;
  f16* W16  = (f16*)(ws);                        // 5 x 512x512 f16 = 2,621,440 B
  f16* pe16 = (f16*)(ws + 2621440);              // 1,048,576 B
  f16* Qf   = (f16*)(ws + 3670016);              // 8,388,608 B (B,H,L,D)
  f16* Kf   = (f16*)(ws + 12058624);             // 8,388,608 B (B,H,L,D)
  f16* Vtf  = (f16*)(ws + 20447232);             // 8,388,608 B (B,H,D,L)
  f16* Pf   = (f16*)(ws + 28835840);             // 1,048,576 B (H,L,D)
  f16* ctx  = (f16*)(ws + 29884416);             // 8,388,608 B (B,L,512)

  prep_kernel<<<2304, 256, 0, stream>>>(Wq, Wk, Wv, Wpos, Wo, W16, pe16);
  gemm_main<<<dim3(64, 4, 4), 256, 0, stream>>>(query, key_in, value, pe16, W16,
                                                bq, bk, bv, Qf, Kf, Vtf, Pf);
  attn_kernel<<<dim3(64, 16, 8), 256, 0, stream>>>(Qf, Kf, Vtf, Pf, ub, vb, ctx);
  gemm_out<<<dim3(64, 4), 256, 0, stream>>>(ctx, W16 + 1048576, bo, out);
}

// Round 8
// 309.807 us; speedup vs baseline: 1.0994x; 1.0994x over previous
//
#include <hip/hip_runtime.h>
#include <hip/hip_bf16.h>
#include <cstddef>

typedef _Float16 f16;
typedef _Float16 f16x8 __attribute__((ext_vector_type(8)));
typedef _Float16 f16x4 __attribute__((ext_vector_type(4)));
typedef _Float16 f16x2 __attribute__((ext_vector_type(2)));
typedef float    f32x4 __attribute__((ext_vector_type(4)));

#define MFMA16(a,b,c) __builtin_amdgcn_mfma_f32_16x16x32_f16((a),(b),(c),0,0,0)

#if __has_builtin(__builtin_amdgcn_exp2f)
#define EXP2(x) __builtin_amdgcn_exp2f(x)
#else
#define EXP2(x) __expf((x) * 0.6931471805599453f)
#endif

__device__ __forceinline__ void gload16(const void* g, void* lds) {
  __builtin_amdgcn_global_load_lds((const __attribute__((address_space(1))) void*)g,
                                   (__attribute__((address_space(3))) void*)lds, 16, 0, 0);
}

// ---------------------------------------------------------------------------
// Convert the 5 weight matrices fp32 -> f16 (Wq, Wk, Wv, Wpos, Wo)
// ---------------------------------------------------------------------------
__global__ __launch_bounds__(256) void conv_w(
    const float* __restrict__ w0, const float* __restrict__ w1,
    const float* __restrict__ w2, const float* __restrict__ w3,
    const float* __restrict__ w4, f16* __restrict__ dst)
{
  const int idx = blockIdx.x * 256 + threadIdx.x;
  const int seg = idx >> 16;
  const int r   = idx & 65535;
  const float* s = seg == 0 ? w0 : seg == 1 ? w1 : seg == 2 ? w2 : seg == 3 ? w3 : w4;
  float4 v = ((const float4*)s)[r];
  f16x4 h = { (f16)v.x, (f16)v.y, (f16)v.z, (f16)v.w };
  ((f16x4*)(dst + ((size_t)seg << 18)))[r] = h;
}

// ---------------------------------------------------------------------------
// Sinusoidal positional embedding, f16 output
// ---------------------------------------------------------------------------
__global__ __launch_bounds__(256) void pe16_kernel(f16* __restrict__ pe) {
  const int l = blockIdx.x;
  const int p = threadIdx.x;
  const float divv = expf(-(logf(10000.0f) * (2.0f * (float)p)) / 512.0f);
  const float ang  = (float)l * divv;
  f16x2 o = { (f16)sinf(ang), (f16)cosf(ang) };
  *(f16x2*)(pe + (size_t)l * 512 + 2 * p) = o;
}

// ---------------------------------------------------------------------------
// 128x128-tile GEMM (m97 structure): BK=64, 4 waves in 2x2, 4x4 fragments.
// z-fused Q/K/V projections (round-6 version, byte-for-byte).
// ---------------------------------------------------------------------------
__global__ __launch_bounds__(256) void gemm128_qkv(
    const float* __restrict__ q_in, const float* __restrict__ k_in,
    const float* __restrict__ v_in, const f16* __restrict__ W16,
    const float* __restrict__ bq, const float* __restrict__ bk,
    const float* __restrict__ bv,
    f16* __restrict__ Qf, f16* __restrict__ Kf, f16* __restrict__ Vtf)
{
  __shared__ __align__(16) char Asm[16384];
  __shared__ __align__(16) char Bsm[16384];

  const int z = blockIdx.z;
  const float* Ap   = z == 0 ? q_in : z == 1 ? k_in : v_in;
  const f16*   Wf   = W16 + (size_t)z * 262144;
  const float* bias = z == 0 ? bq : z == 1 ? bk : bv;
  f16*         Cp   = z == 0 ? Qf : z == 1 ? Kf : Vtf;

  const int tid   = threadIdx.x;
  const int gm0   = blockIdx.x * 128;
  const int gn0   = blockIdx.y * 128;
  const int lane  = tid & 63, w = tid >> 6;
  const int row16 = lane & 15, grp = lane >> 4;
  const int wm = w & 1, wn = w >> 1;
  const int lr8  = lane >> 3;
  const int swcb = ((lane & 7) ^ lr8) * 16;

  f32x4 acc[4][4];
#pragma unroll
  for (int i = 0; i < 4; ++i)
#pragma unroll
    for (int j = 0; j < 4; ++j)
#pragma unroll
      for (int r = 0; r < 4; ++r) acc[i][j][r] = 0.f;

  for (int k0 = 0; k0 < 512; k0 += 64) {
    __syncthreads();
    float4 areg[8];
#pragma unroll
    for (int i = 0; i < 8; ++i) {
      const int u = tid + i * 256;
      const int row = u >> 4, cf = (u & 15) * 4;
      areg[i] = *(const float4*)(Ap + (size_t)(gm0 + row) * 512 + k0 + cf);
    }
#pragma unroll
    for (int i = 0; i < 4; ++i) {
      const int rB = w * 32 + i * 8;
      gload16((const char*)Wf + ((size_t)(gn0 + rB + lr8)) * 1024 + (size_t)k0 * 2 + swcb,
              Bsm + rB * 128);
    }
#pragma unroll
    for (int i = 0; i < 8; ++i) {
      const int u = tid + i * 256;
      const int row = u >> 4, cf = (u & 15) * 4;
      f16x4 hv = { (f16)areg[i].x, (f16)areg[i].y, (f16)areg[i].z, (f16)areg[i].w };
      *(f16x4*)(Asm + row * 128 + ((cf * 2) ^ ((row & 7) * 16))) = hv;
    }
    asm volatile("s_waitcnt vmcnt(0)" ::: "memory");
    __syncthreads();
#pragma unroll
    for (int kk = 0; kk < 64; kk += 32) {
      const int cb = (kk + 8 * grp) * 2;
      f16x8 af[4], bf[4];
#pragma unroll
      for (int f = 0; f < 4; ++f) {
        const int ra = wm * 64 + f * 16 + row16;
        const int rb = wn * 64 + f * 16 + row16;
        af[f] = *(const f16x8*)(Asm + ra * 128 + (cb ^ ((ra & 7) * 16)));
        bf[f] = *(const f16x8*)(Bsm + rb * 128 + (cb ^ ((rb & 7) * 16)));
      }
#pragma unroll
      for (int fi = 0; fi < 4; ++fi)
#pragma unroll
        for (int fj = 0; fj < 4; ++fj)
          acc[fi][fj] = MFMA16(af[fi], bf[fj], acc[fi][fj]);
    }
  }

#pragma unroll
  for (int fi = 0; fi < 4; ++fi)
#pragma unroll
    for (int fj = 0; fj < 4; ++fj) {
      const int gc = gn0 + wn * 64 + fj * 16 + row16;
      const float bval = bias[gc];
#pragma unroll
      for (int r = 0; r < 4; ++r) {
        const int gr = gm0 + wm * 64 + fi * 16 + grp * 4 + r;
        const float v = acc[fi][fj][r] + bval;
        const int b = gr >> 10, l = gr & 1023, h = gc >> 5, d = gc & 31;
        if (z != 2) {
          Cp[(((size_t)(b * 16 + h)) * 1024 + l) * 32 + d] = (f16)v;
        } else {
          Cp[(((size_t)(b * 16 + h)) * 32 + d) * 1024 + l] = (f16)v;
        }
      }
    }
}

// MODE 2: pos GEMM, A=pe16 f16, out f16 (H,L,D) no bias.
// MODE 3: out-proj, A=ctx f16, out fp32 row-major + bias.
template<int MODE>
__global__ __launch_bounds__(256) void gemm128_f16(
    const f16* __restrict__ Ap, const f16* __restrict__ Wf,
    const float* __restrict__ bias, void* __restrict__ Cp)
{
  __shared__ __align__(16) char Asm[16384];
  __shared__ __align__(16) char Bsm[16384];

  const int tid   = threadIdx.x;
  const int gm0   = blockIdx.x * 128;
  const int gn0   = blockIdx.y * 128;
  const int lane  = tid & 63, w = tid >> 6;
  const int row16 = lane & 15, grp = lane >> 4;
  const int wm = w & 1, wn = w >> 1;
  const int lr8  = lane >> 3;
  const int swcb = ((lane & 7) ^ lr8) * 16;

  f32x4 acc[4][4];
#pragma unroll
  for (int i = 0; i < 4; ++i)
#pragma unroll
    for (int j = 0; j < 4; ++j)
#pragma unroll
      for (int r = 0; r < 4; ++r) acc[i][j][r] = 0.f;

  for (int k0 = 0; k0 < 512; k0 += 64) {
    __syncthreads();
#pragma unroll
    for (int i = 0; i < 4; ++i) {
      const int rr = w * 32 + i * 8;
      gload16((const char*)Ap + ((size_t)(gm0 + rr + lr8)) * 1024 + (size_t)k0 * 2 + swcb,
              Asm + rr * 128);
      gload16((const char*)Wf + ((size_t)(gn0 + rr + lr8)) * 1024 + (size_t)k0 * 2 + swcb,
              Bsm + rr * 128);
    }
    asm volatile("s_waitcnt vmcnt(0)" ::: "memory");
    __syncthreads();
#pragma unroll
    for (int kk = 0; kk < 64; kk += 32) {
      const int cb = (kk + 8 * grp) * 2;
      f16x8 af[4], bf[4];
#pragma unroll
      for (int f = 0; f < 4; ++f) {
        const int ra = wm * 64 + f * 16 + row16;
        const int rb = wn * 64 + f * 16 + row16;
        af[f] = *(const f16x8*)(Asm + ra * 128 + (cb ^ ((ra & 7) * 16)));
        bf[f] = *(const f16x8*)(Bsm + rb * 128 + (cb ^ ((rb & 7) * 16)));
      }
#pragma unroll
      for (int fi = 0; fi < 4; ++fi)
#pragma unroll
        for (int fj = 0; fj < 4; ++fj)
          acc[fi][fj] = MFMA16(af[fi], bf[fj], acc[fi][fj]);
    }
  }

#pragma unroll
  for (int fi = 0; fi < 4; ++fi)
#pragma unroll
    for (int fj = 0; fj < 4; ++fj) {
      const int gc = gn0 + wn * 64 + fj * 16 + row16;
      float bval;
      if constexpr (MODE == 2) bval = 0.f; else bval = bias[gc];
#pragma unroll
      for (int r = 0; r < 4; ++r) {
        const int gr = gm0 + wm * 64 + fi * 16 + grp * 4 + r;
        const float v = acc[fi][fj][r] + bval;
        if constexpr (MODE == 2) {
          const int h = gc >> 5, d = gc & 31;
          ((f16*)Cp)[(((size_t)h) * 1024 + gr) * 32 + d] = (f16)v;
        } else {
          ((float*)Cp)[(size_t)gr * 512 + gc] = v;
        }
      }
    }
}

// ---------------------------------------------------------------------------
// Fused rel-pos flash attention.  r7 structure (shuffle-PV, no ptile,
// 35 KB LDS -> 4 blk/CU) + fully address-hoisted shifted-P reads:
//   flat idx = [row16*1028 + w*256 + (1023-l0-row16) + 4*grp]  (vaddr, 1x)
//            + [ti*64 + 16c + r]                                (imm offset)
//   region B (+3) = second vaddr; per-(wave,ti) uniform branch; the one
//   boundary ti falls back to per-element select.
// P_lds pre-scaled by kpre = scale*log2e; p = exp2(fma(st,kpre,sh)).
// ---------------------------------------------------------------------------
__global__ __launch_bounds__(256) void attn_kernel(
    const f16* __restrict__ Qf, const f16* __restrict__ Kf,
    const f16* __restrict__ Vt, const f16* __restrict__ Pos,
    const float* __restrict__ ubias, const float* __restrict__ vbias,
    f16* __restrict__ ctx)
{
  __shared__ f16 P_lds[17][1028];     // unshifted P * kpre, f16

  const int tid   = threadIdx.x;
  const int w     = tid >> 6, lane = tid & 63;
  const int row16 = lane & 15, grp = lane >> 4;
  const int b = blockIdx.z, h = blockIdx.y;
  const int l0 = blockIdx.x * 16;

  const size_t bh = (size_t)(b * 16 + h);
  const f16* Qb = Qf + bh * 1024 * 32;
  const f16* Kb = Kf + bh * 1024 * 32;
  const f16* Vb = Vt + bh * 32 * 1024;
  const f16* Pb = Pos + (size_t)h * 1024 * 32;

  const f32x4 z4 = {0.f, 0.f, 0.f, 0.f};
  const float kpre = 0.0637587157f;   // (1/sqrt(512)) * log2(e)

  // --- Phase 0: Q fragments (q = row16, d = 8*grp+e)
  f16x8 qu, qv, qv2;
  {
    f16x8 qraw = *(const f16x8*)(Qb + (size_t)(l0 + row16) * 32 + 8 * grp);
    const int r2 = l0 + 16 + row16;
    f16x8 q2 = *(const f16x8*)(Qb + (size_t)(r2 < 1024 ? r2 : 1023) * 32 + 8 * grp);
#pragma unroll
    for (int e = 0; e < 8; ++e) {
      const float u = ubias[h * 32 + 8 * grp + e];
      const float v = vbias[h * 32 + 8 * grp + e];
      qu[e]  = (f16)((float)qraw[e] + u);
      qv[e]  = (f16)((float)qraw[e] + v);
      qv2[e] = (f16)((float)q2[e]   + v);
    }
  }

  // zero-pad column (j == 1024)
  if (tid < 17) {
    f16x4 z = {(f16)0.f, (f16)0.f, (f16)0.f, (f16)0.f};
    *(f16x4*)&P_lds[tid][1024] = z;
  }

  // --- Phase 1: unshifted P (pre-scaled by kpre)
#pragma unroll 4
  for (int c = 0; c < 16; ++c) {
    const int jc = w * 16 + c;
    f16x8 pf = *(const f16x8*)(Pb + (size_t)(jc * 16 + row16) * 32 + 8 * grp);
    f32x4 p0 = MFMA16(pf, qv,  z4);
    f32x4 p1 = MFMA16(pf, qv2, z4);
    const int j0 = jc * 16 + grp * 4;
    {
      f16x4 vv = { (f16)(p0[0] * kpre), (f16)(p0[1] * kpre),
                   (f16)(p0[2] * kpre), (f16)(p0[3] * kpre) };
      *(f16x4*)&P_lds[row16][j0] = vv;
    }
    if (row16 == 0) {
      f16x4 vv = { (f16)(p1[0] * kpre), (f16)(p1[1] * kpre),
                   (f16)(p1[2] * kpre), (f16)(p1[3] * kpre) };
      *(f16x4*)&P_lds[16][j0] = vv;
    }
  }
  __syncthreads();

  // --- Phase 2: flash loop, wave-private, no barriers, no max tracking
  float psum = 0.f;
  f32x4 od[2];
#pragma unroll
  for (int hh = 0; hh < 2; ++hh) for (int r = 0; r < 4; ++r) od[hh][r] = 0.f;

  // hoisted shifted-P base pointers (all per-element address math is imm)
  const f16* vA = &P_lds[0][0] + row16 * 1028 + w * 256 + (1023 - l0 - row16) + 4 * grp;
  const f16* vB = vA + 3;
  const int  sbase = row16 + ((grp & 1) << 5);
  const bool hiG   = (grp & 2) != 0;

#pragma unroll
  for (int ti = 0; ti < 4; ++ti) {
    const int mbase = w * 256 + ti * 64;
    f32x4 st[4];
#pragma unroll
    for (int c = 0; c < 4; ++c) {
      f16x8 kf = *(const f16x8*)(Kb + (size_t)(mbase + c * 16 + row16) * 32 + 8 * grp);
      st[c] = MFMA16(kf, qu, z4);
    }

    // shifted-P reads: vaddr + literal offsets; uniform region branch
    float sh[4][4];
    const bool unifB = (mbase >= l0 + 17);
    const bool unifA = (mbase + 62 <= l0);
    if (unifB) {
#pragma unroll
      for (int c = 0; c < 4; ++c)
#pragma unroll
        for (int r = 0; r < 4; ++r) sh[c][r] = (float)vB[ti * 64 + c * 16 + r];
    } else if (unifA) {
#pragma unroll
      for (int c = 0; c < 4; ++c)
#pragma unroll
        for (int r = 0; r < 4; ++r) sh[c][r] = (float)vA[ti * 64 + c * 16 + r];
    } else {
      const int c1 = 1023 - l0 - row16;
      const f16* Prow = &P_lds[row16][0];
#pragma unroll
      for (int c = 0; c < 4; ++c)
#pragma unroll
        for (int r = 0; r < 4; ++r) {
          const int jA = mbase + c * 16 + grp * 4 + r + c1;
          sh[c][r] = (float)Prow[jA + (jA >= 1025 ? 3 : 0)];
        }
    }

    // exp2 -> packed ST-layout pairs X[c][j]
    unsigned X[4][2];
#pragma unroll
    for (int c = 0; c < 4; ++c) {
      float p[4];
#pragma unroll
      for (int r = 0; r < 4; ++r) {
        p[r] = EXP2(fmaf(st[c][r], kpre, sh[c][r]));
        psum += p[r];
      }
      f16x2 t0 = { (f16)p[0], (f16)p[1] };
      f16x2 t1 = { (f16)p[2], (f16)p[3] };
      X[c][0] = __builtin_bit_cast(unsigned, t0);
      X[c][1] = __builtin_bit_cast(unsigned, t1);
    }

    // shuffle-redistribute into K=32 A-fragments, then PV MFMA
#pragma unroll
    for (int kc = 0; kc < 2; ++kc) {
      union { unsigned u[4]; f16x8 v; } pa;
#pragma unroll
      for (int wd = 0; wd < 4; ++wd) {
        const int src = sbase + ((wd >> 1) << 4);
        const unsigned lo = (unsigned)__shfl((int)X[2 * kc][wd & 1], src, 64);
        const unsigned hi = (unsigned)__shfl((int)X[2 * kc + 1][wd & 1], src, 64);
        pa.u[wd] = hiG ? hi : lo;
      }
#pragma unroll
      for (int hh = 0; hh < 2; ++hh) {
        f16x8 vf = *(const f16x8*)(Vb + (size_t)(hh * 16 + row16) * 1024 + mbase + kc * 32 + 8 * grp);
        od[hh] = MFMA16(pa.v, vf, od[hh]);
      }
    }
  }

  float l1 = psum + __shfl_xor(psum, 16);
  l1 += __shfl_xor(l1, 32);

  __syncthreads();
  float* mo = (float*)&P_lds[0][0];    // overlay: [4][16 q][32 d]
  float* ls = mo + 4 * 16 * 32;        // [4][16]
#pragma unroll
  for (int hh = 0; hh < 2; ++hh)
#pragma unroll
    for (int r = 0; r < 4; ++r)
      mo[(w * 16 + grp * 4 + r) * 32 + hh * 16 + row16] = od[hh][r];
  if (grp == 0) ls[w * 16 + row16] = l1;
  __syncthreads();

  const int q = tid >> 4, dp = tid & 15;
  const float Ls = ls[q] + ls[16 + q] + ls[32 + q] + ls[48 + q];
  float o0 = 0.f, o1 = 0.f;
#pragma unroll
  for (int ww = 0; ww < 4; ++ww) {
    o0 += mo[(ww * 16 + q) * 32 + 2 * dp];
    o1 += mo[(ww * 16 + q) * 32 + 2 * dp + 1];
  }
  const float inv = 1.f / Ls;
  const size_t oidx = ((size_t)(b * 1024 + l0 + q)) * 512 + h * 32 + 2 * dp;
  f16x2 o2 = { (f16)(o0 * inv), (f16)(o1 * inv) };
  *(f16x2*)(ctx + oidx) = o2;
}

// ---------------------------------------------------------------------------
extern "C" void kernel_launch(void* const* d_in, const int* in_sizes, int n_in,
                              void* d_out, int out_size, void* d_ws, size_t ws_size,
                              hipStream_t stream) {
  const float* query  = (const float*)d_in[0];
  const float* key_in = (const float*)d_in[1];
  const float* value  = (const float*)d_in[2];
  const float* Wq = (const float*)d_in[3];
  const float* bq = (const float*)d_in[4];
  const float* Wk = (const float*)d_in[5];
  const float* bk = (const float*)d_in[6];
  const float* Wv = (const float*)d_in[7];
  const float* bv = (const float*)d_in[8];
  const float* Wpos = (const float*)d_in[9];
  const float* ub   = (const float*)d_in[10];
  const float* vb   = (const float*)d_in[11];
  const float* Wo = (const float*)d_in[12];
  const float* bo = (const float*)d_in[13];
  float* out = (float*)d_out;

  char* ws = (char*)d_ws;
  f16* W16  = (f16*)(ws);                        // 5 x 512x512 f16 = 2,621,440 B
  f16* pe16 = (f16*)(ws + 2621440);              // 1,048,576 B
  f16* Qf   = (f16*)(ws + 3670016);              // 8,388,608 B (B,H,L,D)
  f16* Kf   = (f16*)(ws + 12058624);             // 8,388,608 B (B,H,L,D)
  f16* Vtf  = (f16*)(ws + 20447232);             // 8,388,608 B (B,H,D,L)
  f16* Pf   = (f16*)(ws + 28835840);             // 1,048,576 B (H,L,D)
  f16* ctx  = (f16*)(ws + 29884416);             // 8,388,608 B (B,L,512)

  conv_w<<<1280, 256, 0, stream>>>(Wq, Wk, Wv, Wpos, Wo, W16);
  pe16_kernel<<<1024, 256, 0, stream>>>(pe16);
  gemm128_qkv<<<dim3(64, 4, 3), 256, 0, stream>>>(query, key_in, value, W16,
                                                  bq, bk, bv, Qf, Kf, Vtf);
  gemm128_f16<2><<<dim3(8,  4), 256, 0, stream>>>(pe16, W16 + 786432, nullptr, Pf);
  attn_kernel<<<dim3(64, 16, 8), 256, 0, stream>>>(Qf, Kf, Vtf, Pf, ub, vb, ctx);
  gemm128_f16<3><<<dim3(64, 4), 256, 0, stream>>>(ctx, W16 + 1048576, bo, out);
}